// Round 9
// baseline (162.803 us; speedup 1.0000x reference)
//
#include <hip/hip_runtime.h>

typedef unsigned short u16;
typedef unsigned int   u32;
typedef __attribute__((ext_vector_type(8))) short short8;   // 8 bf16 = 4 VGPRs
typedef __attribute__((ext_vector_type(4))) float f32x4;

#define NB    4      // batch
#define NCH   256    // channels
#define NHD   8      // heads
#define HD    32     // head dim
#define NSP   2304   // H*W
#define NBH   32     // NB*NHD
#define NKT   36     // total 64-wide K tiles
#define KPW   9      // K tiles per wave (4-wave in-block k-split)

// round-to-nearest-even fp32 -> bf16 bits
__device__ __forceinline__ u16 f2bf(float f) {
    u32 u = __float_as_uint(f);
    u += 0x7FFFu + ((u >> 16) & 1u);
    return (u16)(u >> 16);
}
__device__ __forceinline__ u32 pack2(float a, float b) {
    return (u32)f2bf(a) | ((u32)f2bf(b) << 16);
}
// fast pack two fp32 -> bf16x2: hw cvt (RNE) if present, else 1-instr v_perm truncate.
__device__ __forceinline__ u32 pkfast(float a, float b) {
#if __has_builtin(__builtin_amdgcn_cvt_pk_bf16_f32)
    typedef __attribute__((ext_vector_type(2))) __bf16 bf2;
    union { bf2 v; u32 u; } cv;
    cv.v = __builtin_amdgcn_cvt_pk_bf16_f32(a, b);
    return cv.u;
#else
    return __builtin_amdgcn_perm(__float_as_uint(b), __float_as_uint(a), 0x07060302u);
#endif
}
__device__ __forceinline__ float fexp2(float x) {
#if __has_builtin(__builtin_amdgcn_exp2f)
    return __builtin_amdgcn_exp2f(x);
#else
    return exp2f(x);
#endif
}
// exp2(relu(x)) — the softmax numerator (temp*log2e folded into q upstream)
__device__ __forceinline__ float er(float x) { return fexp2(fmaxf(x, 0.f)); }

// ---------------- prep: normalize q,k (temp*log2e folded into q); v -> sigma-permuted
// tiles; p==3 slice casts proj_w -> bf16.
// Two spatial columns per thread (float2 loads halve VMEM instr count vs scalar).
// grid (6, 4, NBH), block 192: 6*192*2 = 2304 = NSP.
__global__ __launch_bounds__(192) void prep_kernel(
    const float* __restrict__ qkv, const float* __restrict__ temp,
    const float* __restrict__ projw,
    u16* __restrict__ Qn, u16* __restrict__ Kn, u16* __restrict__ Vp,
    u16* __restrict__ Wb)
{
    const int p  = blockIdx.y;
    const int bh = blockIdx.z, b = bh >> 3, head = bh & 7;

    if (p == 3) {   // proj_w cast: 16384 float4 chunks spread over 6*32 blocks
        const int idx = (bh * 6 + blockIdx.x) * 192 + threadIdx.x;
        if (idx < NCH * NCH / 4) {
            float4 v = ((const float4*)projw)[idx];
            ((uint2*)Wb)[idx] = make_uint2(pack2(v.x, v.y), pack2(v.z, v.w));
        }
        return;
    }

    const int i  = blockIdx.x * 192 + threadIdx.x;   // [0, 1152)
    const int n0 = i * 2;                            // even spatial index; pair (n0, n0+1)
    const float* src = qkv + ((size_t)(b * 3 * NCH + p * NCH + head * HD)) * NSP + n0;

    float2 v[HD];
#pragma unroll
    for (int d = 0; d < HD; ++d) v[d] = *(const float2*)(src + (size_t)d * NSP);

    if (p == 2) {
        // V tile layout: Vp[bh][kt][d*64 + c*32 + quad*8 + jj]; for even n0 the pair
        // (n0, n0+1) maps to adjacent u16 slots -> one aligned u32 store.
        const int tile = n0 >> 6, loc = n0 & 63;
        const int c = loc >> 5, r5 = loc & 31;
        const int qd  = (r5 < 16) ? (r5 >> 2) : ((r5 - 16) >> 2);
        const int jj  = (r5 < 16) ? (r5 & 3) : (4 + (r5 & 3));
        u16* dst = Vp + (size_t)bh * NSP * HD + (size_t)tile * 2048 + c * 32 + qd * 8 + jj;
#pragma unroll
        for (int d = 0; d < HD; ++d) *(u32*)(dst + d * 64) = pack2(v[d].x, v[d].y);
    } else {
        float s0 = 0.f, s1 = 0.f;
#pragma unroll
        for (int d = 0; d < HD; ++d) { s0 += v[d].x * v[d].x; s1 += v[d].y * v[d].y; }
        float sc0 = 1.f / fmaxf(sqrtf(s0), 1e-12f);
        float sc1 = 1.f / fmaxf(sqrtf(s1), 1e-12f);
        if (p == 0) {   // fold temp*log2e into q
            const float t = temp[head] * 1.44269504088896f;
            sc0 *= t; sc1 *= t;
        }
        u32 pk[HD];   // [0..15] row n0, [16..31] row n0+1
#pragma unroll
        for (int j = 0; j < HD / 2; ++j) pk[j]          = pack2(v[2 * j].x * sc0, v[2 * j + 1].x * sc0);
#pragma unroll
        for (int j = 0; j < HD / 2; ++j) pk[HD / 2 + j] = pack2(v[2 * j].y * sc1, v[2 * j + 1].y * sc1);
        u16* dst = (p == 0 ? Qn : Kn) + ((size_t)bh * NSP + n0) * HD;   // 2 rows = 128 B contiguous
#pragma unroll
        for (int j = 0; j < 8; ++j) ((uint4*)dst)[j] = ((const uint4*)pk)[j];
    }
}

// ---------------- flash attention: 64 q-rows/wave, 4-way k-split, barrier-free K-loop ----
// block = 256 thr (4 waves), grid (NBH, NSP/64). blockIdx.x = bh so all q-blocks of a bh
// share one XCD -> K/V L2-resident.
// STRUCTURE (settled r0-r8): t2=4 chains/wave, 4-way k-split, MFMA rowsum, ping-pong
// K+V prefetch, ~156 unified regs -> 3 waves/SIMD. Occupancy-buying variants LOST
// (r3,r5); V-prefetch null (r7); setprio-removal + lag-1 pipeline WON (r8: 52.8->49.8).
// r9: FLAT cross-tile software pipeline. r8's lag-1 reset at each tile boundary: tail
// ran two consecutive finishes (no S-block between), head ran two consecutive S-blocks
// (no finish between) — 2/8 slots per tile un-overlapped. Now the stream is a strict
// finish/sblock alternation across all 36 (kt,t2) stages: the last two S-blocks of
// tile kt's segment are P(kt+1,0),P(kt+1,1) using the already-prefetched next-K
// buffer. Single fill (prologue) + drain (tile 8). Zero register change.
__device__ __forceinline__ void sblock(const short8 (&kc)[4], const short8& q, f32x4 (&sf)[4]) {
    const f32x4 zf = {0.f, 0.f, 0.f, 0.f};
#pragma unroll
    for (int i = 0; i < 4; ++i)
        sf[i] = __builtin_amdgcn_mfma_f32_16x16x32_bf16(kc[i], q, zf, 0, 0, 0);
}
__device__ __forceinline__ void finish(const f32x4 (&sf)[4], const short8 (&vc)[2][2],
                                       f32x4 (&oT)[2], f32x4& rT) {
    const short one = (short)0x3F80;   // bf16 1.0
    const short8 vones = {one, one, one, one, one, one, one, one};
#pragma unroll
    for (int c = 0; c < 2; ++c) {
        union { short8 s; u32 u[4]; } pa;
        pa.u[0] = pkfast(er(sf[2 * c][0]),     er(sf[2 * c][1]));
        pa.u[1] = pkfast(er(sf[2 * c][2]),     er(sf[2 * c][3]));
        pa.u[2] = pkfast(er(sf[2 * c + 1][0]), er(sf[2 * c + 1][1]));
        pa.u[3] = pkfast(er(sf[2 * c + 1][2]), er(sf[2 * c + 1][3]));
        oT[0] = __builtin_amdgcn_mfma_f32_16x16x32_bf16(pa.s, vc[c][0], oT[0], 0, 0, 0);
        oT[1] = __builtin_amdgcn_mfma_f32_16x16x32_bf16(pa.s, vc[c][1], oT[1], 0, 0, 0);
        rT    = __builtin_amdgcn_mfma_f32_16x16x32_bf16(pa.s, vones,    rT,    0, 0, 0);
    }
}
// one tile's steady-state segment of the flat pipeline:
//   [pref tile kt+1 -> knxt/vnxt]
//   F(kt,0) P(kt,2)   F(kt,1) P(kt,3)   F(kt,2) [P(kt+1,0)]   F(kt,3) [P(kt+1,1)]
// On entry sfA/sfB hold S(kt,0)/S(kt,1); on exit they hold S(kt+1,0)/S(kt+1,1).
__device__ __forceinline__ void steady(
    const u16* __restrict__ Kg, const u16* __restrict__ Vg, int kt, bool pref, bool nxt,
    short8 (&kcur)[4], short8 (&vcur)[2][2],
    short8 (&knxt)[4], short8 (&vnxt)[2][2],
    const short8 (&qf)[4],
    f32x4 (&oacc)[4][2], f32x4 (&rsac)[4],
    f32x4 (&sfA)[4], f32x4 (&sfB)[4])
{
    if (pref) {
#pragma unroll
        for (int i = 0; i < 4; ++i)
            knxt[i] = *(const short8*)(Kg + (size_t)(kt + 1) * 2048 + i * 512);
#pragma unroll
        for (int c = 0; c < 2; ++c)
#pragma unroll
            for (int h = 0; h < 2; ++h)
                vnxt[c][h] = *(const short8*)(Vg + (size_t)(kt + 1) * 2048 + h * 1024 + c * 32);
    }
    finish(sfA, vcur, oacc[0], rsac[0]);  sblock(kcur, qf[2], sfA);
    finish(sfB, vcur, oacc[1], rsac[1]);  sblock(kcur, qf[3], sfB);
    finish(sfA, vcur, oacc[2], rsac[2]);  if (nxt) sblock(knxt, qf[0], sfA);
    finish(sfB, vcur, oacc[3], rsac[3]);  if (nxt) sblock(knxt, qf[1], sfB);
}

__global__ __launch_bounds__(256) void attn_kernel(
    const u16* __restrict__ Qn, const u16* __restrict__ Kn,
    const u16* __restrict__ Vp, u16* __restrict__ X)
{
    __shared__ float cmb[4][64][49];   // [wave][lane][t2*12 + {8 O0,O1 | 4 rs}] pad 49
    const int bh = blockIdx.x, b = bh >> 3, head = bh & 7;
    const int w = threadIdx.x >> 6, lane = threadIdx.x & 63;
    const int l15 = lane & 15, quad = lane >> 4;
    const int qbase = blockIdx.y * 64;

    const u16* Kg = Kn + (size_t)bh * NSP * HD + (size_t)w * KPW * 2048 + l15 * HD + quad * 8;
    const u16* Vg = Vp + (size_t)bh * NSP * HD + (size_t)w * KPW * 2048 + l15 * 64 + quad * 8;

    short8 qf[4];
#pragma unroll
    for (int t2 = 0; t2 < 4; ++t2)
        qf[t2] = *(const short8*)(Qn + ((size_t)bh * NSP + qbase + t2 * 16 + l15) * HD + quad * 8);

    f32x4 oacc[4][2] = {{{0,0,0,0},{0,0,0,0}},{{0,0,0,0},{0,0,0,0}},
                        {{0,0,0,0},{0,0,0,0}},{{0,0,0,0},{0,0,0,0}}};
    f32x4 rsac[4]    = {{0,0,0,0},{0,0,0,0},{0,0,0,0},{0,0,0,0}};

    // preload K and V tile 0 into the 'a' role buffers; a/b alternate per tile
    short8 ka[4], kb[4];
    short8 va[2][2], vb[2][2];
#pragma unroll
    for (int i = 0; i < 4; ++i) ka[i] = *(const short8*)(Kg + i * 512);
#pragma unroll
    for (int c = 0; c < 2; ++c)
#pragma unroll
        for (int h = 0; h < 2; ++h)
            va[c][h] = *(const short8*)(Vg + h * 1024 + c * 32);

    // pipeline fill: S(0,0) S(0,1)
    f32x4 sfA[4], sfB[4];
    sblock(ka, qf[0], sfA);
    sblock(ka, qf[1], sfB);

    // steady tiles 0..7 (pair-unrolled for static buffer roles), drain on tile 8
    for (int kt = 0; kt < KPW - 1; kt += 2) {
        steady(Kg, Vg, kt,     true, true, ka, va, kb, vb, qf, oacc, rsac, sfA, sfB);
        steady(Kg, Vg, kt + 1, true, true, kb, vb, ka, va, qf, oacc, rsac, sfA, sfB);
    }
    steady(Kg, Vg, KPW - 1, false, false, ka, va, kb, vb, qf, oacc, rsac, sfA, sfB);

    // publish all partials; wave w reduces + writes q-tile t2 == w
    {
        float* my = &cmb[w][lane][0];
#pragma unroll
        for (int t2 = 0; t2 < 4; ++t2) {
#pragma unroll
            for (int h = 0; h < 2; ++h)
#pragma unroll
                for (int r = 0; r < 4; ++r) my[t2 * 12 + h * 4 + r] = oacc[t2][h][r];
#pragma unroll
            for (int r = 0; r < 4; ++r) my[t2 * 12 + 8 + r] = rsac[t2][r];
        }
    }
    __syncthreads();
    {
        const int t2 = w;
        float o0[4] = {0,0,0,0}, o1[4] = {0,0,0,0}, rsum[4] = {0,0,0,0};
#pragma unroll
        for (int j = 0; j < 4; ++j) {
            const float* srcp = &cmb[j][lane][t2 * 12];
#pragma unroll
            for (int r = 0; r < 4; ++r) {
                o0[r]   += srcp[r];
                o1[r]   += srcp[4 + r];
                rsum[r] += srcp[8 + r];
            }
        }
        u16* Xb = X + (size_t)b * NSP * NCH + head * HD;
#pragma unroll
        for (int r = 0; r < 4; ++r) {
            const float inv = 1.f / rsum[r];
            u16* row = Xb + (size_t)(qbase + t2 * 16 + quad * 4 + r) * NCH;
            row[l15]      = f2bf(o0[r] * inv);
            row[16 + l15] = f2bf(o1[r] * inv);
        }
    }
}

// ---------------- 1x1 conv: out[b,o,n] = sum_c W[o,c] X[b,n,c] + bias[o] ----------------
// grid (NSP/32, NCH/64, NB), block 256 (4 waves): wave w does o-tile blockIdx.y*64+w*16,
// all 4 waves share the same 32-row X tile -> L1 reuse.
__global__ __launch_bounds__(256) void proj_kernel(
    const u16* __restrict__ Wb, const u16* __restrict__ X,
    const float* __restrict__ bias, float* __restrict__ out)
{
    const int b = blockIdx.z;
    const int w = threadIdx.x >> 6, lane = threadIdx.x & 63;
    const int l15 = lane & 15, quad = lane >> 4;
    const int obase = blockIdx.y * 64 + w * 16;
    const int nbase = blockIdx.x * 32;

    const u16* wrow = Wb + (size_t)(obase + l15) * NCH + quad * 8;
    const u16* xrow = X + ((size_t)b * NSP + nbase + l15) * NCH + quad * 8;

    f32x4 acc[2] = {{0,0,0,0},{0,0,0,0}};
#pragma unroll
    for (int ks = 0; ks < 8; ++ks) {
        const short8 af = *(const short8*)(wrow + ks * 32);
        acc[0] = __builtin_amdgcn_mfma_f32_16x16x32_bf16(af, *(const short8*)(xrow + ks * 32), acc[0], 0, 0, 0);
        acc[1] = __builtin_amdgcn_mfma_f32_16x16x32_bf16(af, *(const short8*)(xrow + (size_t)16 * NCH + ks * 32), acc[1], 0, 0, 0);
    }
#pragma unroll
    for (int r = 0; r < 4; ++r) {
        const int o = obase + quad * 4 + r;
        const float bo = bias[o];
        float* orow = out + ((size_t)b * NCH + o) * NSP + nbase;
        orow[l15]      = acc[0][r] + bo;
        orow[16 + l15] = acc[1][r] + bo;
    }
}

extern "C" void kernel_launch(void* const* d_in, const int* in_sizes, int n_in,
                              void* d_out, int out_size, void* d_ws, size_t ws_size,
                              hipStream_t stream) {
    const float* qkv   = (const float*)d_in[0];
    const float* temp  = (const float*)d_in[1];
    const float* projw = (const float*)d_in[2];
    const float* projb = (const float*)d_in[3];
    float* out = (float*)d_out;

    // workspace: Qn | Kn | Vp | X (each 2,359,296 bf16) | Wb (65,536 bf16)  ~19 MB
    u16* Qn = (u16*)d_ws;
    u16* Kn = Qn + (size_t)NBH * NSP * HD;
    u16* Vp = Kn + (size_t)NBH * NSP * HD;
    u16* X  = Vp + (size_t)NBH * NSP * HD;
    u16* Wb = X + (size_t)NB * NSP * NCH;

    prep_kernel<<<dim3(6, 4, NBH), dim3(192), 0, stream>>>(qkv, temp, projw, Qn, Kn, Vp, Wb);
    attn_kernel<<<dim3(NBH, NSP / 64), dim3(256), 0, stream>>>(Qn, Kn, Vp, X);
    proj_kernel<<<dim3(NSP / 32, NCH / 64, NB), dim3(256), 0, stream>>>(Wb, X, projb, out);
}

// Round 10
// 161.532 us; speedup vs baseline: 1.0079x; 1.0079x over previous
//
#include <hip/hip_runtime.h>

typedef unsigned short u16;
typedef unsigned int   u32;
typedef __attribute__((ext_vector_type(8))) short short8;   // 8 bf16 = 4 VGPRs
typedef __attribute__((ext_vector_type(4))) float f32x4;

#define NB    4      // batch
#define NCH   256    // channels
#define NHD   8      // heads
#define HD    32     // head dim
#define NSP   2304   // H*W
#define NBH   32     // NB*NHD
#define NKT   36     // total 64-wide K tiles
#define KPW   9      // K tiles per wave (4-wave in-block k-split)

// round-to-nearest-even fp32 -> bf16 bits
__device__ __forceinline__ u16 f2bf(float f) {
    u32 u = __float_as_uint(f);
    u += 0x7FFFu + ((u >> 16) & 1u);
    return (u16)(u >> 16);
}
__device__ __forceinline__ u32 pack2(float a, float b) {
    return (u32)f2bf(a) | ((u32)f2bf(b) << 16);
}
// fast pack two fp32 -> bf16x2: hw cvt (RNE) if present, else 1-instr v_perm truncate.
__device__ __forceinline__ u32 pkfast(float a, float b) {
#if __has_builtin(__builtin_amdgcn_cvt_pk_bf16_f32)
    typedef __attribute__((ext_vector_type(2))) __bf16 bf2;
    union { bf2 v; u32 u; } cv;
    cv.v = __builtin_amdgcn_cvt_pk_bf16_f32(a, b);
    return cv.u;
#else
    return __builtin_amdgcn_perm(__float_as_uint(b), __float_as_uint(a), 0x07060302u);
#endif
}
__device__ __forceinline__ float fexp2(float x) {
#if __has_builtin(__builtin_amdgcn_exp2f)
    return __builtin_amdgcn_exp2f(x);
#else
    return exp2f(x);
#endif
}
// exp2(relu(x)) — the softmax numerator (temp*log2e folded into q upstream)
__device__ __forceinline__ float er(float x) { return fexp2(fmaxf(x, 0.f)); }

// ---------------- prep: normalize q,k (temp*log2e folded into q); v -> sigma-permuted
// tiles; p==3 slice casts proj_w -> bf16.
// Two spatial columns per thread (float2 loads halve VMEM instr count vs scalar).
// grid (6, 4, NBH), block 192: 6*192*2 = 2304 = NSP.
__global__ __launch_bounds__(192) void prep_kernel(
    const float* __restrict__ qkv, const float* __restrict__ temp,
    const float* __restrict__ projw,
    u16* __restrict__ Qn, u16* __restrict__ Kn, u16* __restrict__ Vp,
    u16* __restrict__ Wb)
{
    const int p  = blockIdx.y;
    const int bh = blockIdx.z, b = bh >> 3, head = bh & 7;

    if (p == 3) {   // proj_w cast: 16384 float4 chunks spread over 6*32 blocks
        const int idx = (bh * 6 + blockIdx.x) * 192 + threadIdx.x;
        if (idx < NCH * NCH / 4) {
            float4 v = ((const float4*)projw)[idx];
            ((uint2*)Wb)[idx] = make_uint2(pack2(v.x, v.y), pack2(v.z, v.w));
        }
        return;
    }

    const int i  = blockIdx.x * 192 + threadIdx.x;   // [0, 1152)
    const int n0 = i * 2;                            // even spatial index; pair (n0, n0+1)
    const float* src = qkv + ((size_t)(b * 3 * NCH + p * NCH + head * HD)) * NSP + n0;

    float2 v[HD];
#pragma unroll
    for (int d = 0; d < HD; ++d) v[d] = *(const float2*)(src + (size_t)d * NSP);

    if (p == 2) {
        // V tile layout: Vp[bh][kt][d*64 + c*32 + quad*8 + jj]; for even n0 the pair
        // (n0, n0+1) maps to adjacent u16 slots -> one aligned u32 store.
        const int tile = n0 >> 6, loc = n0 & 63;
        const int c = loc >> 5, r5 = loc & 31;
        const int qd  = (r5 < 16) ? (r5 >> 2) : ((r5 - 16) >> 2);
        const int jj  = (r5 < 16) ? (r5 & 3) : (4 + (r5 & 3));
        u16* dst = Vp + (size_t)bh * NSP * HD + (size_t)tile * 2048 + c * 32 + qd * 8 + jj;
#pragma unroll
        for (int d = 0; d < HD; ++d) *(u32*)(dst + d * 64) = pack2(v[d].x, v[d].y);
    } else {
        float s0 = 0.f, s1 = 0.f;
#pragma unroll
        for (int d = 0; d < HD; ++d) { s0 += v[d].x * v[d].x; s1 += v[d].y * v[d].y; }
        float sc0 = 1.f / fmaxf(sqrtf(s0), 1e-12f);
        float sc1 = 1.f / fmaxf(sqrtf(s1), 1e-12f);
        if (p == 0) {   // fold temp*log2e into q
            const float t = temp[head] * 1.44269504088896f;
            sc0 *= t; sc1 *= t;
        }
        u32 pk[HD];   // [0..15] row n0, [16..31] row n0+1
#pragma unroll
        for (int j = 0; j < HD / 2; ++j) pk[j]          = pack2(v[2 * j].x * sc0, v[2 * j + 1].x * sc0);
#pragma unroll
        for (int j = 0; j < HD / 2; ++j) pk[HD / 2 + j] = pack2(v[2 * j].y * sc1, v[2 * j + 1].y * sc1);
        u16* dst = (p == 0 ? Qn : Kn) + ((size_t)bh * NSP + n0) * HD;   // 2 rows = 128 B contiguous
#pragma unroll
        for (int j = 0; j < 8; ++j) ((uint4*)dst)[j] = ((const uint4*)pk)[j];
    }
}

// ---------------- flash attention: 64 q-rows/wave, 4-way k-split, barrier-free K-loop ----
// block = 256 thr (4 waves), grid (NBH, NSP/64). blockIdx.x = bh so all q-blocks of a bh
// share one XCD -> K/V L2-resident.
// STRUCTURE (settled r0-r9): t2=4 chains/wave, 4-way k-split, MFMA rowsum, ping-pong
// K+V buffers, 3 waves/SIMD tier (total regs <= 170, i.e. arch <= ~122 with 48 acc).
// r8 (lag-1 pipeline, 49.8us) is the reference. r9's flat cross-tile pipeline had the
// right mechanism but issued BOTH prefetches at the segment top where sfA/sfB are live
// -> 140 arch VGPR -> 2-wave tier -> 65us. r10 = flat pipeline with LIVENESS-STAGGERED
// prefetch: K(kt+1) at segment top (vnxt not yet live; used 3 finish-slots later,
// ~450cyc), V(kt+1) at mid-segment where kcur just died (used ~400cyc later at next
// segment's F0). Peak liveness ~96 data regs, r8-level. Telltale of tier drop:
// OccupancyPercent < 12 -> revert to r8.
__device__ __forceinline__ void sblock(const short8 (&kc)[4], const short8& q, f32x4 (&sf)[4]) {
    const f32x4 zf = {0.f, 0.f, 0.f, 0.f};
#pragma unroll
    for (int i = 0; i < 4; ++i)
        sf[i] = __builtin_amdgcn_mfma_f32_16x16x32_bf16(kc[i], q, zf, 0, 0, 0);
}
__device__ __forceinline__ void finish(const f32x4 (&sf)[4], const short8 (&vc)[2][2],
                                       f32x4 (&oT)[2], f32x4& rT) {
    const short one = (short)0x3F80;   // bf16 1.0
    const short8 vones = {one, one, one, one, one, one, one, one};
#pragma unroll
    for (int c = 0; c < 2; ++c) {
        union { short8 s; u32 u[4]; } pa;
        pa.u[0] = pkfast(er(sf[2 * c][0]),     er(sf[2 * c][1]));
        pa.u[1] = pkfast(er(sf[2 * c][2]),     er(sf[2 * c][3]));
        pa.u[2] = pkfast(er(sf[2 * c + 1][0]), er(sf[2 * c + 1][1]));
        pa.u[3] = pkfast(er(sf[2 * c + 1][2]), er(sf[2 * c + 1][3]));
        oT[0] = __builtin_amdgcn_mfma_f32_16x16x32_bf16(pa.s, vc[c][0], oT[0], 0, 0, 0);
        oT[1] = __builtin_amdgcn_mfma_f32_16x16x32_bf16(pa.s, vc[c][1], oT[1], 0, 0, 0);
        rT    = __builtin_amdgcn_mfma_f32_16x16x32_bf16(pa.s, vones,    rT,    0, 0, 0);
    }
}
// one tile's steady-state segment of the flat pipeline:
//   [pref K(kt+1)]
//   F(kt,0) P(kt,2)   F(kt,1) P(kt,3)
//   [pref V(kt+1)]                       <- kcur dead here; vnxt live only from here
//   F(kt,2) [P(kt+1,0)]   F(kt,3) [P(kt+1,1)]
// On entry sfA/sfB hold S(kt,0)/S(kt,1); on exit they hold S(kt+1,0)/S(kt+1,1).
__device__ __forceinline__ void steady(
    const u16* __restrict__ Kg, const u16* __restrict__ Vg, int kt, bool pref, bool nxt,
    short8 (&kcur)[4], short8 (&vcur)[2][2],
    short8 (&knxt)[4], short8 (&vnxt)[2][2],
    const short8 (&qf)[4],
    f32x4 (&oacc)[4][2], f32x4 (&rsac)[4],
    f32x4 (&sfA)[4], f32x4 (&sfB)[4])
{
    if (pref) {
#pragma unroll
        for (int i = 0; i < 4; ++i)
            knxt[i] = *(const short8*)(Kg + (size_t)(kt + 1) * 2048 + i * 512);
    }
    finish(sfA, vcur, oacc[0], rsac[0]);  sblock(kcur, qf[2], sfA);
    finish(sfB, vcur, oacc[1], rsac[1]);  sblock(kcur, qf[3], sfB);
    if (pref) {
#pragma unroll
        for (int c = 0; c < 2; ++c)
#pragma unroll
            for (int h = 0; h < 2; ++h)
                vnxt[c][h] = *(const short8*)(Vg + (size_t)(kt + 1) * 2048 + h * 1024 + c * 32);
    }
    finish(sfA, vcur, oacc[2], rsac[2]);  if (nxt) sblock(knxt, qf[0], sfA);
    finish(sfB, vcur, oacc[3], rsac[3]);  if (nxt) sblock(knxt, qf[1], sfB);
}

__global__ __launch_bounds__(256) void attn_kernel(
    const u16* __restrict__ Qn, const u16* __restrict__ Kn,
    const u16* __restrict__ Vp, u16* __restrict__ X)
{
    __shared__ float cmb[4][64][49];   // [wave][lane][t2*12 + {8 O0,O1 | 4 rs}] pad 49
    const int bh = blockIdx.x, b = bh >> 3, head = bh & 7;
    const int w = threadIdx.x >> 6, lane = threadIdx.x & 63;
    const int l15 = lane & 15, quad = lane >> 4;
    const int qbase = blockIdx.y * 64;

    const u16* Kg = Kn + (size_t)bh * NSP * HD + (size_t)w * KPW * 2048 + l15 * HD + quad * 8;
    const u16* Vg = Vp + (size_t)bh * NSP * HD + (size_t)w * KPW * 2048 + l15 * 64 + quad * 8;

    short8 qf[4];
#pragma unroll
    for (int t2 = 0; t2 < 4; ++t2)
        qf[t2] = *(const short8*)(Qn + ((size_t)bh * NSP + qbase + t2 * 16 + l15) * HD + quad * 8);

    f32x4 oacc[4][2] = {{{0,0,0,0},{0,0,0,0}},{{0,0,0,0},{0,0,0,0}},
                        {{0,0,0,0},{0,0,0,0}},{{0,0,0,0},{0,0,0,0}}};
    f32x4 rsac[4]    = {{0,0,0,0},{0,0,0,0},{0,0,0,0},{0,0,0,0}};

    // preload K and V tile 0 into the 'a' role buffers; a/b alternate per tile
    short8 ka[4], kb[4];
    short8 va[2][2], vb[2][2];
#pragma unroll
    for (int i = 0; i < 4; ++i) ka[i] = *(const short8*)(Kg + i * 512);
#pragma unroll
    for (int c = 0; c < 2; ++c)
#pragma unroll
        for (int h = 0; h < 2; ++h)
            va[c][h] = *(const short8*)(Vg + h * 1024 + c * 32);

    // pipeline fill: S(0,0) S(0,1)
    f32x4 sfA[4], sfB[4];
    sblock(ka, qf[0], sfA);
    sblock(ka, qf[1], sfB);

    // steady tiles 0..7 (pair-unrolled for static buffer roles), drain on tile 8
    for (int kt = 0; kt < KPW - 1; kt += 2) {
        steady(Kg, Vg, kt,     true, true, ka, va, kb, vb, qf, oacc, rsac, sfA, sfB);
        steady(Kg, Vg, kt + 1, true, true, kb, vb, ka, va, qf, oacc, rsac, sfA, sfB);
    }
    steady(Kg, Vg, KPW - 1, false, false, ka, va, kb, vb, qf, oacc, rsac, sfA, sfB);

    // publish all partials; wave w reduces + writes q-tile t2 == w
    {
        float* my = &cmb[w][lane][0];
#pragma unroll
        for (int t2 = 0; t2 < 4; ++t2) {
#pragma unroll
            for (int h = 0; h < 2; ++h)
#pragma unroll
                for (int r = 0; r < 4; ++r) my[t2 * 12 + h * 4 + r] = oacc[t2][h][r];
#pragma unroll
            for (int r = 0; r < 4; ++r) my[t2 * 12 + 8 + r] = rsac[t2][r];
        }
    }
    __syncthreads();
    {
        const int t2 = w;
        float o0[4] = {0,0,0,0}, o1[4] = {0,0,0,0}, rsum[4] = {0,0,0,0};
#pragma unroll
        for (int j = 0; j < 4; ++j) {
            const float* srcp = &cmb[j][lane][t2 * 12];
#pragma unroll
            for (int r = 0; r < 4; ++r) {
                o0[r]   += srcp[r];
                o1[r]   += srcp[4 + r];
                rsum[r] += srcp[8 + r];
            }
        }
        u16* Xb = X + (size_t)b * NSP * NCH + head * HD;
#pragma unroll
        for (int r = 0; r < 4; ++r) {
            const float inv = 1.f / rsum[r];
            u16* row = Xb + (size_t)(qbase + t2 * 16 + quad * 4 + r) * NCH;
            row[l15]      = f2bf(o0[r] * inv);
            row[16 + l15] = f2bf(o1[r] * inv);
        }
    }
}

// ---------------- 1x1 conv: out[b,o,n] = sum_c W[o,c] X[b,n,c] + bias[o] ----------------
// grid (NSP/32, NCH/64, NB), block 256 (4 waves): wave w does o-tile blockIdx.y*64+w*16,
// all 4 waves share the same 32-row X tile -> L1 reuse.
__global__ __launch_bounds__(256) void proj_kernel(
    const u16* __restrict__ Wb, const u16* __restrict__ X,
    const float* __restrict__ bias, float* __restrict__ out)
{
    const int b = blockIdx.z;
    const int w = threadIdx.x >> 6, lane = threadIdx.x & 63;
    const int l15 = lane & 15, quad = lane >> 4;
    const int obase = blockIdx.y * 64 + w * 16;
    const int nbase = blockIdx.x * 32;

    const u16* wrow = Wb + (size_t)(obase + l15) * NCH + quad * 8;
    const u16* xrow = X + ((size_t)b * NSP + nbase + l15) * NCH + quad * 8;

    f32x4 acc[2] = {{0,0,0,0},{0,0,0,0}};
#pragma unroll
    for (int ks = 0; ks < 8; ++ks) {
        const short8 af = *(const short8*)(wrow + ks * 32);
        acc[0] = __builtin_amdgcn_mfma_f32_16x16x32_bf16(af, *(const short8*)(xrow + ks * 32), acc[0], 0, 0, 0);
        acc[1] = __builtin_amdgcn_mfma_f32_16x16x32_bf16(af, *(const short8*)(xrow + (size_t)16 * NCH + ks * 32), acc[1], 0, 0, 0);
    }
#pragma unroll
    for (int r = 0; r < 4; ++r) {
        const int o = obase + quad * 4 + r;
        const float bo = bias[o];
        float* orow = out + ((size_t)b * NCH + o) * NSP + nbase;
        orow[l15]      = acc[0][r] + bo;
        orow[16 + l15] = acc[1][r] + bo;
    }
}

extern "C" void kernel_launch(void* const* d_in, const int* in_sizes, int n_in,
                              void* d_out, int out_size, void* d_ws, size_t ws_size,
                              hipStream_t stream) {
    const float* qkv   = (const float*)d_in[0];
    const float* temp  = (const float*)d_in[1];
    const float* projw = (const float*)d_in[2];
    const float* projb = (const float*)d_in[3];
    float* out = (float*)d_out;

    // workspace: Qn | Kn | Vp | X (each 2,359,296 bf16) | Wb (65,536 bf16)  ~19 MB
    u16* Qn = (u16*)d_ws;
    u16* Kn = Qn + (size_t)NBH * NSP * HD;
    u16* Vp = Kn + (size_t)NBH * NSP * HD;
    u16* X  = Vp + (size_t)NBH * NSP * HD;
    u16* Wb = X + (size_t)NB * NSP * NCH;

    prep_kernel<<<dim3(6, 4, NBH), dim3(192), 0, stream>>>(qkv, temp, projw, Qn, Kn, Vp, Wb);
    attn_kernel<<<dim3(NBH, NSP / 64), dim3(256), 0, stream>>>(Qn, Kn, Vp, X);
    proj_kernel<<<dim3(NSP / 32, NCH / 64, NB), dim3(256), 0, stream>>>(Wb, X, projb, out);
}

// Round 11
// 145.622 us; speedup vs baseline: 1.1180x; 1.1093x over previous
//
#include <hip/hip_runtime.h>

typedef unsigned short u16;
typedef unsigned int   u32;
typedef __attribute__((ext_vector_type(8))) short short8;   // 8 bf16 = 4 VGPRs
typedef __attribute__((ext_vector_type(4))) float f32x4;

#define NB    4      // batch
#define NCH   256    // channels
#define NHD   8      // heads
#define HD    32     // head dim
#define NSP   2304   // H*W
#define NBH   32     // NB*NHD
#define NKT   36     // total 64-wide K tiles
#define KPW   9      // K tiles per wave (4-wave in-block k-split)

// round-to-nearest-even fp32 -> bf16 bits
__device__ __forceinline__ u16 f2bf(float f) {
    u32 u = __float_as_uint(f);
    u += 0x7FFFu + ((u >> 16) & 1u);
    return (u16)(u >> 16);
}
__device__ __forceinline__ u32 pack2(float a, float b) {
    return (u32)f2bf(a) | ((u32)f2bf(b) << 16);
}
// fast pack two fp32 -> bf16x2: hw cvt (RNE) if present, else 1-instr v_perm truncate.
__device__ __forceinline__ u32 pkfast(float a, float b) {
#if __has_builtin(__builtin_amdgcn_cvt_pk_bf16_f32)
    typedef __attribute__((ext_vector_type(2))) __bf16 bf2;
    union { bf2 v; u32 u; } cv;
    cv.v = __builtin_amdgcn_cvt_pk_bf16_f32(a, b);
    return cv.u;
#else
    return __builtin_amdgcn_perm(__float_as_uint(b), __float_as_uint(a), 0x07060302u);
#endif
}
__device__ __forceinline__ float fexp2(float x) {
#if __has_builtin(__builtin_amdgcn_exp2f)
    return __builtin_amdgcn_exp2f(x);
#else
    return exp2f(x);
#endif
}
// exp2(relu(x)) — the softmax numerator (temp*log2e folded into q upstream)
__device__ __forceinline__ float er(float x) { return fexp2(fmaxf(x, 0.f)); }

// ---------------- prep: normalize q,k (temp*log2e folded into q); v -> sigma-permuted
// tiles; p==3 slice casts proj_w -> bf16.
// Two spatial columns per thread (float2 loads halve VMEM instr count vs scalar).
// grid (6, 4, NBH), block 192: 6*192*2 = 2304 = NSP.
__global__ __launch_bounds__(192) void prep_kernel(
    const float* __restrict__ qkv, const float* __restrict__ temp,
    const float* __restrict__ projw,
    u16* __restrict__ Qn, u16* __restrict__ Kn, u16* __restrict__ Vp,
    u16* __restrict__ Wb)
{
    const int p  = blockIdx.y;
    const int bh = blockIdx.z, b = bh >> 3, head = bh & 7;

    if (p == 3) {   // proj_w cast: 16384 float4 chunks spread over 6*32 blocks
        const int idx = (bh * 6 + blockIdx.x) * 192 + threadIdx.x;
        if (idx < NCH * NCH / 4) {
            float4 v = ((const float4*)projw)[idx];
            ((uint2*)Wb)[idx] = make_uint2(pack2(v.x, v.y), pack2(v.z, v.w));
        }
        return;
    }

    const int i  = blockIdx.x * 192 + threadIdx.x;   // [0, 1152)
    const int n0 = i * 2;                            // even spatial index; pair (n0, n0+1)
    const float* src = qkv + ((size_t)(b * 3 * NCH + p * NCH + head * HD)) * NSP + n0;

    float2 v[HD];
#pragma unroll
    for (int d = 0; d < HD; ++d) v[d] = *(const float2*)(src + (size_t)d * NSP);

    if (p == 2) {
        // V tile layout: Vp[bh][kt][d*64 + c*32 + quad*8 + jj]; for even n0 the pair
        // (n0, n0+1) maps to adjacent u16 slots -> one aligned u32 store.
        const int tile = n0 >> 6, loc = n0 & 63;
        const int c = loc >> 5, r5 = loc & 31;
        const int qd  = (r5 < 16) ? (r5 >> 2) : ((r5 - 16) >> 2);
        const int jj  = (r5 < 16) ? (r5 & 3) : (4 + (r5 & 3));
        u16* dst = Vp + (size_t)bh * NSP * HD + (size_t)tile * 2048 + c * 32 + qd * 8 + jj;
#pragma unroll
        for (int d = 0; d < HD; ++d) *(u32*)(dst + d * 64) = pack2(v[d].x, v[d].y);
    } else {
        float s0 = 0.f, s1 = 0.f;
#pragma unroll
        for (int d = 0; d < HD; ++d) { s0 += v[d].x * v[d].x; s1 += v[d].y * v[d].y; }
        float sc0 = 1.f / fmaxf(sqrtf(s0), 1e-12f);
        float sc1 = 1.f / fmaxf(sqrtf(s1), 1e-12f);
        if (p == 0) {   // fold temp*log2e into q
            const float t = temp[head] * 1.44269504088896f;
            sc0 *= t; sc1 *= t;
        }
        u32 pk[HD];   // [0..15] row n0, [16..31] row n0+1
#pragma unroll
        for (int j = 0; j < HD / 2; ++j) pk[j]          = pack2(v[2 * j].x * sc0, v[2 * j + 1].x * sc0);
#pragma unroll
        for (int j = 0; j < HD / 2; ++j) pk[HD / 2 + j] = pack2(v[2 * j].y * sc1, v[2 * j + 1].y * sc1);
        u16* dst = (p == 0 ? Qn : Kn) + ((size_t)bh * NSP + n0) * HD;   // 2 rows = 128 B contiguous
#pragma unroll
        for (int j = 0; j < 8; ++j) ((uint4*)dst)[j] = ((const uint4*)pk)[j];
    }
}

// ---------------- flash attention: 64 q-rows/wave, 4-way k-split, barrier-free K-loop ----
// block = 256 thr (4 waves), grid (NBH, NSP/64). blockIdx.x = bh so all q-blocks of a bh
// share one XCD -> K/V L2-resident.
// FINAL STRUCTURE (r0-r10 map): t2=4 chains/wave, 4-way k-split, MFMA rowsum, ping-pong
// K+V prefetch issued in the sf-dead window, lag-1 software pipeline WITHIN each body,
// no setprio (scheduling-region fences hurt). 108 arch + 48 acc ~ 156 regs = exactly
// inside the 3-waves/SIMD tier (<=170).
// Measured dead ends: occupancy via smaller per-wave state (r3,r5: ILP loss > residency
// gain); forced register caps (r1,r4: spills); cross-boundary flat pipeline (r9,r10:
// sfA/sfB live across segments -> 175+ regs -> 2-wave tier, structural).
__device__ __forceinline__ void sblock(const short8 (&kc)[4], const short8& q, f32x4 (&sf)[4]) {
    const f32x4 zf = {0.f, 0.f, 0.f, 0.f};
#pragma unroll
    for (int i = 0; i < 4; ++i)
        sf[i] = __builtin_amdgcn_mfma_f32_16x16x32_bf16(kc[i], q, zf, 0, 0, 0);
}
__device__ __forceinline__ void finish(const f32x4 (&sf)[4], const short8 (&vc)[2][2],
                                       f32x4 (&oT)[2], f32x4& rT) {
    const short one = (short)0x3F80;   // bf16 1.0
    const short8 vones = {one, one, one, one, one, one, one, one};
#pragma unroll
    for (int c = 0; c < 2; ++c) {
        union { short8 s; u32 u[4]; } pa;
        pa.u[0] = pkfast(er(sf[2 * c][0]),     er(sf[2 * c][1]));
        pa.u[1] = pkfast(er(sf[2 * c][2]),     er(sf[2 * c][3]));
        pa.u[2] = pkfast(er(sf[2 * c + 1][0]), er(sf[2 * c + 1][1]));
        pa.u[3] = pkfast(er(sf[2 * c + 1][2]), er(sf[2 * c + 1][3]));
        oT[0] = __builtin_amdgcn_mfma_f32_16x16x32_bf16(pa.s, vc[c][0], oT[0], 0, 0, 0);
        oT[1] = __builtin_amdgcn_mfma_f32_16x16x32_bf16(pa.s, vc[c][1], oT[1], 0, 0, 0);
        rT    = __builtin_amdgcn_mfma_f32_16x16x32_bf16(pa.s, vones,    rT,    0, 0, 0);
    }
}
__device__ __forceinline__ void kbody(
    const u16* __restrict__ Kg, const u16* __restrict__ Vg, int kt, bool pf,
    short8 (&kc)[4], short8 (&kn)[4],
    short8 (&vc)[2][2], short8 (&vn)[2][2],
    const short8 (&qf)[4],
    f32x4 (&oacc)[4][2], f32x4 (&rsac)[4])
{
    // prefetch K and V for NEXT tile into the other role buffers (no copy-back).
    // sfA/sfB are dead here (local to the body) — this placement keeps peak liveness
    // at ~108 arch regs; hoisting it into a live-sf window costs the 3-wave tier.
    if (pf) {
#pragma unroll
        for (int i = 0; i < 4; ++i)
            kn[i] = *(const short8*)(Kg + (size_t)(kt + 1) * 2048 + i * 512);
#pragma unroll
        for (int c = 0; c < 2; ++c)
#pragma unroll
            for (int h = 0; h < 2; ++h)
                vn[c][h] = *(const short8*)(Vg + (size_t)(kt + 1) * 2048 + h * 1024 + c * 32);
    }

    // lag-1 pipeline over t2: S(t2+1) issues before finish(t2) consumes sf(t2).
    f32x4 sfA[4], sfB[4];
    sblock(kc, qf[0], sfA);
    sblock(kc, qf[1], sfB);
    finish(sfA, vc, oacc[0], rsac[0]);
    sblock(kc, qf[2], sfA);
    finish(sfB, vc, oacc[1], rsac[1]);
    sblock(kc, qf[3], sfB);
    finish(sfA, vc, oacc[2], rsac[2]);
    finish(sfB, vc, oacc[3], rsac[3]);
}

__global__ __launch_bounds__(256) void attn_kernel(
    const u16* __restrict__ Qn, const u16* __restrict__ Kn,
    const u16* __restrict__ Vp, u16* __restrict__ X)
{
    __shared__ float cmb[4][64][49];   // [wave][lane][t2*12 + {8 O0,O1 | 4 rs}] pad 49
    const int bh = blockIdx.x, b = bh >> 3, head = bh & 7;
    const int w = threadIdx.x >> 6, lane = threadIdx.x & 63;
    const int l15 = lane & 15, quad = lane >> 4;
    const int qbase = blockIdx.y * 64;

    const u16* Kg = Kn + (size_t)bh * NSP * HD + (size_t)w * KPW * 2048 + l15 * HD + quad * 8;
    const u16* Vg = Vp + (size_t)bh * NSP * HD + (size_t)w * KPW * 2048 + l15 * 64 + quad * 8;

    short8 qf[4];
#pragma unroll
    for (int t2 = 0; t2 < 4; ++t2)
        qf[t2] = *(const short8*)(Qn + ((size_t)bh * NSP + qbase + t2 * 16 + l15) * HD + quad * 8);

    f32x4 oacc[4][2] = {{{0,0,0,0},{0,0,0,0}},{{0,0,0,0},{0,0,0,0}},
                        {{0,0,0,0},{0,0,0,0}},{{0,0,0,0},{0,0,0,0}}};
    f32x4 rsac[4]    = {{0,0,0,0},{0,0,0,0},{0,0,0,0},{0,0,0,0}};

    // preload K and V tile 0 into the 'a' role buffers; a/b alternate per body
    short8 ka[4], kb[4];
    short8 va[2][2], vb[2][2];
#pragma unroll
    for (int i = 0; i < 4; ++i) ka[i] = *(const short8*)(Kg + i * 512);
#pragma unroll
    for (int c = 0; c < 2; ++c)
#pragma unroll
        for (int h = 0; h < 2; ++h)
            va[c][h] = *(const short8*)(Vg + h * 1024 + c * 32);

    // KPW=9: pairs (0,1)(2,3)(4,5)(6,7) + peeled tail 8. Body(kt) consumes its K/V
    // buffers and prefetches tile kt+1 into the OTHER buffers — no copy-back moves.
    for (int kt = 0; kt < KPW - 1; kt += 2) {
        kbody(Kg, Vg, kt,     true,  ka, kb, va, vb, qf, oacc, rsac);
        kbody(Kg, Vg, kt + 1, true,  kb, ka, vb, va, qf, oacc, rsac);
    }
    kbody(Kg, Vg, KPW - 1, false, ka, kb, va, vb, qf, oacc, rsac);

    // publish all partials; wave w reduces + writes q-tile t2 == w
    {
        float* my = &cmb[w][lane][0];
#pragma unroll
        for (int t2 = 0; t2 < 4; ++t2) {
#pragma unroll
            for (int h = 0; h < 2; ++h)
#pragma unroll
                for (int r = 0; r < 4; ++r) my[t2 * 12 + h * 4 + r] = oacc[t2][h][r];
#pragma unroll
            for (int r = 0; r < 4; ++r) my[t2 * 12 + 8 + r] = rsac[t2][r];
        }
    }
    __syncthreads();
    {
        const int t2 = w;
        float o0[4] = {0,0,0,0}, o1[4] = {0,0,0,0}, rsum[4] = {0,0,0,0};
#pragma unroll
        for (int j = 0; j < 4; ++j) {
            const float* srcp = &cmb[j][lane][t2 * 12];
#pragma unroll
            for (int r = 0; r < 4; ++r) {
                o0[r]   += srcp[r];
                o1[r]   += srcp[4 + r];
                rsum[r] += srcp[8 + r];
            }
        }
        u16* Xb = X + (size_t)b * NSP * NCH + head * HD;
#pragma unroll
        for (int r = 0; r < 4; ++r) {
            const float inv = 1.f / rsum[r];
            u16* row = Xb + (size_t)(qbase + t2 * 16 + quad * 4 + r) * NCH;
            row[l15]      = f2bf(o0[r] * inv);
            row[16 + l15] = f2bf(o1[r] * inv);
        }
    }
}

// ---------------- 1x1 conv: out[b,o,n] = sum_c W[o,c] X[b,n,c] + bias[o] ----------------
// grid (NSP/32, NCH/64, NB), block 256 (4 waves): wave w does o-tile blockIdx.y*64+w*16,
// all 4 waves share the same 32-row X tile -> L1 reuse.
__global__ __launch_bounds__(256) void proj_kernel(
    const u16* __restrict__ Wb, const u16* __restrict__ X,
    const float* __restrict__ bias, float* __restrict__ out)
{
    const int b = blockIdx.z;
    const int w = threadIdx.x >> 6, lane = threadIdx.x & 63;
    const int l15 = lane & 15, quad = lane >> 4;
    const int obase = blockIdx.y * 64 + w * 16;
    const int nbase = blockIdx.x * 32;

    const u16* wrow = Wb + (size_t)(obase + l15) * NCH + quad * 8;
    const u16* xrow = X + ((size_t)b * NSP + nbase + l15) * NCH + quad * 8;

    f32x4 acc[2] = {{0,0,0,0},{0,0,0,0}};
#pragma unroll
    for (int ks = 0; ks < 8; ++ks) {
        const short8 af = *(const short8*)(wrow + ks * 32);
        acc[0] = __builtin_amdgcn_mfma_f32_16x16x32_bf16(af, *(const short8*)(xrow + ks * 32), acc[0], 0, 0, 0);
        acc[1] = __builtin_amdgcn_mfma_f32_16x16x32_bf16(af, *(const short8*)(xrow + (size_t)16 * NCH + ks * 32), acc[1], 0, 0, 0);
    }
#pragma unroll
    for (int r = 0; r < 4; ++r) {
        const int o = obase + quad * 4 + r;
        const float bo = bias[o];
        float* orow = out + ((size_t)b * NCH + o) * NSP + nbase;
        orow[l15]      = acc[0][r] + bo;
        orow[16 + l15] = acc[1][r] + bo;
    }
}

extern "C" void kernel_launch(void* const* d_in, const int* in_sizes, int n_in,
                              void* d_out, int out_size, void* d_ws, size_t ws_size,
                              hipStream_t stream) {
    const float* qkv   = (const float*)d_in[0];
    const float* temp  = (const float*)d_in[1];
    const float* projw = (const float*)d_in[2];
    const float* projb = (const float*)d_in[3];
    float* out = (float*)d_out;

    // workspace: Qn | Kn | Vp | X (each 2,359,296 bf16) | Wb (65,536 bf16)  ~19 MB
    u16* Qn = (u16*)d_ws;
    u16* Kn = Qn + (size_t)NBH * NSP * HD;
    u16* Vp = Kn + (size_t)NBH * NSP * HD;
    u16* X  = Vp + (size_t)NBH * NSP * HD;
    u16* Wb = X + (size_t)NB * NSP * NCH;

    prep_kernel<<<dim3(6, 4, NBH), dim3(192), 0, stream>>>(qkv, temp, projw, Qn, Kn, Vp, Wb);
    attn_kernel<<<dim3(NBH, NSP / 64), dim3(256), 0, stream>>>(Qn, Kn, Vp, X);
    proj_kernel<<<dim3(NSP / 32, NCH / 64, NB), dim3(256), 0, stream>>>(Wb, X, projb, out);
}